// Round 10
// baseline (219.773 us; speedup 1.0000x reference)
//
#include <hip/hip_runtime.h>
#include <hip/hip_bf16.h>
#include <math.h>

constexpr int B = 2, T = 2048, C = 1024, H = 16, D = 64;
constexpr int M = B * T;          // 4096
// 1/sqrt(64) * log2(e): scores premultiplied so softmax uses exp2 (1 VALU op)
constexpr float SCALE_L2E = 0.125f * 1.4426950408889634f;

typedef __attribute__((ext_vector_type(8))) short s16x8;  // 8 bf16 = 4 VGPRs
typedef __attribute__((ext_vector_type(4))) short s16x4;
typedef __attribute__((ext_vector_type(4))) float fv4;

typedef unsigned short ushort_t;

// cheap RNE fp32->bf16 (no NaN path; inputs are never NaN here).
static __device__ __forceinline__ ushort_t f2bf(float x) {
    union { float f; unsigned u; } c; c.f = x;
    unsigned u = c.u + 0x7FFFu + ((c.u >> 16) & 1u);
    return (ushort_t)(u >> 16);
}

// packed RNE fp32x2 -> bf16x2 (single VALU op; same rounding as f2bf)
static __device__ __forceinline__ int cvt_pk_bf16(float lo, float hi) {
    int r;
    asm("v_cvt_pk_bf16_f32 %0, %1, %2" : "=v"(r) : "v"(lo), "v"(hi));
    return r;
}

// global->LDS async copy, 16B per lane. LDS dest is WAVE-UNIFORM base +
// lane*16B (m104/m108) — pass a wave-uniform lp!
#define GLDS(gp, lp) __builtin_amdgcn_global_load_lds( \
    (const __attribute__((address_space(1))) void*)(gp), \
    (__attribute__((address_space(3))) void*)(lp), 16, 0, 0)

// ---------------------------------------------------------------------------
// prep: transpose + convert weights only (QKV staging eliminated — gemm_qkv
// reads f32 inputs directly). Wt[s*1024 + n][k] = Ws[k][n], bf16. 1024 blocks.
// ---------------------------------------------------------------------------
__global__ __launch_bounds__(256) void prep(
    const float* __restrict__ W0, const float* __restrict__ W1,
    const float* __restrict__ W2, const float* __restrict__ W3,
    ushort_t* __restrict__ Wt)
{
    __shared__ ushort_t tile[64][72];
    const int tid = threadIdx.x;
    const int idx = blockIdx.x;                 // 0..1023
    const int s = idx >> 8;                     // 0..3
    const float* W = (s == 0) ? W0 : (s == 1) ? W1 : (s == 2) ? W2 : W3;
    const int k0 = (idx & 15) * 64, n0 = ((idx >> 4) & 15) * 64;
#pragma unroll
    for (int it = 0; it < 4; it++) {
        int f = it * 256 + tid;
        int r = f >> 4, c4 = (f & 15) * 4;
        float4 x = *(const float4*)(W + (size_t)(k0 + r) * C + n0 + c4);
        *(int*)&tile[r][c4]     = cvt_pk_bf16(x.x, x.y);
        *(int*)&tile[r][c4 + 2] = cvt_pk_bf16(x.z, x.w);
    }
    __syncthreads();
#pragma unroll
    for (int it = 0; it < 4; it++) {
        int f = it * 256 + tid;
        int rr = f >> 4, c4 = (f & 15) * 4;
        union { s16x4 v; ushort_t u[4]; } u;
#pragma unroll
        for (int j = 0; j < 4; j++) u.u[j] = tile[c4 + j][rr];
        *(s16x4*)(Wt + (size_t)(s * 1024 + n0 + rr) * 1024 + k0 + c4) = u.v;
    }
}

// ---------------------------------------------------------------------------
// Fused QKV projection GEMM. A staged as RAW F32 via global_load_lds directly
// from Q/K/V (prep convert round-trip eliminated, −48MB HBM net):
//   - f32 A-tile rows are 128B -> 16B-chunk c^(row&7) swizzle (attn-proven;
//     linear would be 16-way bank-conflicted). Pre-swizzled GLDS source,
//     matching XOR on the ds_read_b128 pair.
//   - fragment read converts f32->bf16 in-reg (4x cvt_pk; VALU was 7% busy).
//     Same RNE rounding as before -> bit-identical results.
//   - counted-vmcnt double-barrier (round-9 attn-proven): prefetch's 6 GLDS
//     stay in flight across the barrier; vmcnt(6) waits only the prior tile.
// LDS 48KB (A f32 32KB + B bf16 16KB) -> 3 blocks/CU = grid residency.
// XCD-aware remap: XCD x owns m0 in {4x..4x+3}; order (s, m0, nt).
// V-section (s==2) transposes its 128x128 output tile through LDS (34KB,
// aliases the 48KB) and writes vt with 256B-contiguous rows.
// ---------------------------------------------------------------------------
__global__ __launch_bounds__(256) void gemm_qkv(
    const float* __restrict__ Qf, const float* __restrict__ Kf,
    const float* __restrict__ Vf, const ushort_t* __restrict__ Wt,
    const float* __restrict__ bq, const float* __restrict__ bk,
    const float* __restrict__ bv,
    ushort_t* __restrict__ qw, ushort_t* __restrict__ kw,
    ushort_t* __restrict__ vt)
{
    __shared__ alignas(16) ushort_t sm[24576];   // 48KB
    float* Asf = (float*)sm;                     // [2][128*32] f32, swizzled (32KB)
    ushort_t* Bs0 = sm + 16384;                  // [2][128*32] bf16 (16KB)

    const int tid = threadIdx.x;
    const int w = tid >> 6, lane = tid & 63;
    const int quad = lane >> 4, lc = lane & 15;
    const int wm = w & 1, wn = w >> 1;
    const int c7 = lc & 7;

    // XCD-aware remap (dispatch round-robins lin%8 across XCDs)
    const int lin = blockIdx.y * 24 + blockIdx.x;    // 0..767
    const int xcd = lin % 8;
    const int i_ = lin / 8;                          // 0..95
    const int s = i_ >> 5;                           // 0,1,2
    const int r_ = i_ & 31;
    const int m0 = (xcd * 4 + (r_ >> 3)) * 128;
    const int nt = s * 8 + (r_ & 7);                 // 0..23
    const int nsec0 = (nt & 7) * 128;

    const float* Af = (s == 0) ? Qf : (s == 1) ? Kf : Vf;
    const ushort_t* Btbase = Wt + (size_t)nt * 128 * 1024;

    // B staging map (bf16, linear 64B rows — unchanged)
    const int srow = (w << 4) + (lane >> 2);
    const int ske  = (lane & 3) * 8;

    // A staging map (f32): 8 rows x 8 chunks(16B=4 floats) per GLDS;
    // lane fetches global chunk (lane&7)^r8 -> LDS holds swizzled layout.
    const int r8 = lane >> 3;                   // 0..7
    const int sca = ((lane & 7) ^ r8) * 4;      // swizzled float offset in k-tile

    fv4 acc[4][4] = {};

    auto stage = [&](int k0, int buf) {
#pragma unroll
        for (int i = 0; i < 4; i++) {           // A: wave w owns rows [w*32, w*32+32)
            int row = w * 32 + i * 8 + r8;
            GLDS(Af + (size_t)(m0 + row) * 1024 + k0 + sca,
                 Asf + buf * 4096 + (w * 32 + i * 8) * 32);
        }
#pragma unroll
        for (int i = 0; i < 2; i++) {           // B as before
            int row = i * 64 + srow;
            GLDS(Btbase + (size_t)row * 1024 + k0 + ske,
                 Bs0 + buf * 4096 + i * 2048 + w * 512);
        }
    };

    stage(0, 0);   // 6 GLDS per wave

    for (int kt = 0; kt < 32; kt++) {
        const int cur = kt & 1;
        const int k0 = kt * 32;
        if (kt + 1 < 32) {
            stage(k0 + 32, cur ^ 1);
            asm volatile("s_waitcnt vmcnt(6)" ::: "memory");   // tile kt done
        } else {
            asm volatile("s_waitcnt vmcnt(0)" ::: "memory");
        }
        __builtin_amdgcn_s_barrier();
        __builtin_amdgcn_sched_barrier(0);

        s16x8 af[4], bf[4];
#pragma unroll
        for (int ms = 0; ms < 4; ms++) {
            const int row = wm * 64 + ms * 16 + lc;        // row&7 == lc&7
            const float* ap = Asf + cur * 4096 + row * 32;
            fv4 x0 = *(const fv4*)(ap + ((( 2 * quad)     ^ c7) << 2));
            fv4 x1 = *(const fv4*)(ap + ((( 2 * quad + 1) ^ c7) << 2));
            union { s16x8 v; int i2[4]; } u;
            u.i2[0] = cvt_pk_bf16(x0[0], x0[1]);
            u.i2[1] = cvt_pk_bf16(x0[2], x0[3]);
            u.i2[2] = cvt_pk_bf16(x1[0], x1[1]);
            u.i2[3] = cvt_pk_bf16(x1[2], x1[3]);
            af[ms] = u.v;
        }
#pragma unroll
        for (int ns = 0; ns < 4; ns++)
            bf[ns] = *(const s16x8*)(Bs0 + cur * 4096 + (wn * 64 + ns * 16 + lc) * 32 + quad * 8);
#pragma unroll
        for (int ms = 0; ms < 4; ms++)
#pragma unroll
            for (int ns = 0; ns < 4; ns++)
                acc[ms][ns] = __builtin_amdgcn_mfma_f32_16x16x32_bf16(
                    af[ms], bf[ns], acc[ms][ns], 0, 0, 0);
        __builtin_amdgcn_s_barrier();
    }

    if (s == 2) {
        // V: transpose 128x128 tile through LDS, then coalesced vt stores.
        ushort_t* tp = sm;                 // [128 n][136 m], 34KB (aliases 48KB)
#pragma unroll
        for (int ns = 0; ns < 4; ns++) {
            const int nl = wn * 64 + ns * 16 + lc;
            const float bias = bv[nsec0 + nl];
#pragma unroll
            for (int ms = 0; ms < 4; ms++) {
                const int ml = wm * 64 + ms * 16 + quad * 4;
                union { s16x4 v; int i2[2]; } u;
                u.i2[0] = cvt_pk_bf16(acc[ms][ns][0] + bias, acc[ms][ns][1] + bias);
                u.i2[1] = cvt_pk_bf16(acc[ms][ns][2] + bias, acc[ms][ns][3] + bias);
                *(s16x4*)&tp[nl * 136 + ml] = u.v;
            }
        }
        __syncthreads();
        const int b_ = m0 >> 11, t0 = m0 & 2047;
        // 128 n-rows x 128 m-cols: 8 iters x 256 threads x 8 elems = 16384
#pragma unroll
        for (int it = 0; it < 8; it++) {
            const int row = it * 16 + (tid >> 4);    // n-local 0..127
            const int ch = tid & 15;                 // m chunk 0..15
            const int n = nsec0 + row;
            const int h_ = n >> 6, d_ = n & 63;
            s16x8 v8 = *(const s16x8*)&tp[row * 136 + ch * 8];
            *(s16x8*)(vt + ((size_t)(b_ * H + h_) * 64 + d_) * T + t0 + ch * 8) = v8;
        }
        return;
    }

    const float* biasp = (s == 0) ? bq : bk;
    const float premul = (s == 0) ? SCALE_L2E : 1.0f;
    ushort_t* outp = (s == 0) ? qw : kw;

#pragma unroll
    for (int ns = 0; ns < 4; ns++) {
        const int nl = nsec0 + wn * 64 + ns * 16 + lc;
        const float bias = biasp[nl];
        const int h_ = nl >> 6, d_ = nl & 63;
#pragma unroll
        for (int ms = 0; ms < 4; ms++) {
#pragma unroll
            for (int r = 0; r < 4; r++) {
                int m = m0 + wm * 64 + ms * 16 + quad * 4 + r;
                float val = (acc[ms][ns][r] + bias) * premul;
                int b_ = m >> 11, t_ = m & (T - 1);
                size_t bh = (size_t)(b_ * H + h_);
                outp[((bh * T + t_) << 6) + d_] = f2bf(val);
            }
        }
    }
}

// ---------------------------------------------------------------------------
// Final projection: out = o(4096x1024)bf16 @ Wot^T + bo, fp32 out.
// BK=64 + chunk^(row&7) swizzled 128B-row LDS (round-8 proven), now with the
// counted-vmcnt double-barrier (prefetch in flight across the barrier).
// XCD-aware remap: XCD x owns m0 in {4x..4x+3}, n inner. LDS 48KB.
// ---------------------------------------------------------------------------
__global__ __launch_bounds__(256) void gemm_final(
    const ushort_t* __restrict__ A, const ushort_t* __restrict__ Wot,
    const float* __restrict__ bo, float* __restrict__ out)
{
    __shared__ alignas(16) ushort_t As[2][128 * 64];   // 32KB, rows 128B
    __shared__ alignas(16) ushort_t Bs[2][64 * 64];    // 16KB, rows 128B

    const int tid = threadIdx.x;
    const int w = tid >> 6, lane = tid & 63;
    const int quad = lane >> 4, lc = lane & 15;
    const int wm = w & 1, wn = w >> 1;
    const int c7 = lc & 7;

    const int lin = blockIdx.y * 16 + blockIdx.x;    // 0..511
    const int xcd = lin & 7;
    const int i_ = lin >> 3;                         // 0..63
    const int m0 = (xcd * 4 + (i_ >> 4)) * 128;
    const int n0 = (i_ & 15) * 64;

    // staging lane map: 8 rows x 8 chunks per GLDS; fetch chunk (lane&7)^r8
    const int r8 = lane >> 3;                  // row within 8-row group
    const int sch = (lane & 7) ^ r8;           // pre-swizzled global chunk

    fv4 acc[4][2] = {};

    auto stage = [&](int k0, int buf) {
#pragma unroll
        for (int i = 0; i < 4; i++) {          // A: wave w owns rows [w*32, w*32+32)
            int row = w * 32 + i * 8 + r8;
            GLDS(A + (size_t)(m0 + row) * 1024 + k0 + sch * 8,
                 As[buf] + (w * 32 + i * 8) * 64);
        }
#pragma unroll
        for (int i = 0; i < 2; i++) {          // B: wave w owns rows [w*16, w*16+16)
            int row = w * 16 + i * 8 + r8;
            GLDS(Wot + (size_t)(n0 + row) * 1024 + k0 + sch * 8,
                 Bs[buf] + (w * 16 + i * 8) * 64);
        }
    };

    stage(0, 0);   // 6 GLDS per wave

    for (int kt = 0; kt < 16; kt++) {
        const int cur = kt & 1;
        const int k0 = kt * 64;
        if (kt + 1 < 16) {
            stage(k0 + 64, cur ^ 1);
            asm volatile("s_waitcnt vmcnt(6)" ::: "memory");   // tile kt done
        } else {
            asm volatile("s_waitcnt vmcnt(0)" ::: "memory");
        }
        __builtin_amdgcn_s_barrier();
        __builtin_amdgcn_sched_barrier(0);

        s16x8 af[4][2], bf[2][2];
#pragma unroll
        for (int ms = 0; ms < 4; ms++) {
            const int row = wm * 64 + ms * 16 + lc;    // row&7 == lc&7
#pragma unroll
            for (int kh = 0; kh < 2; kh++)
                af[ms][kh] = *(const s16x8*)(As[cur] + row * 64
                                             + (((kh * 4 + quad) ^ c7) << 3));
        }
#pragma unroll
        for (int ns = 0; ns < 2; ns++) {
            const int row = wn * 32 + ns * 16 + lc;    // row&7 == lc&7
#pragma unroll
            for (int kh = 0; kh < 2; kh++)
                bf[ns][kh] = *(const s16x8*)(Bs[cur] + row * 64
                                             + (((kh * 4 + quad) ^ c7) << 3));
        }
#pragma unroll
        for (int ms = 0; ms < 4; ms++)
#pragma unroll
            for (int ns = 0; ns < 2; ns++)
#pragma unroll
                for (int kh = 0; kh < 2; kh++)
                    acc[ms][ns] = __builtin_amdgcn_mfma_f32_16x16x32_bf16(
                        af[ms][kh], bf[ns][kh], acc[ms][ns], 0, 0, 0);
        __builtin_amdgcn_s_barrier();
    }

#pragma unroll
    for (int ns = 0; ns < 2; ns++) {
        const int n = n0 + wn * 32 + ns * 16 + lc;
        const float bias = bo[n];
#pragma unroll
        for (int ms = 0; ms < 4; ms++) {
#pragma unroll
            for (int r = 0; r < 4; r++) {
                int m = m0 + wm * 64 + ms * 16 + quad * 4 + r;
                out[(size_t)m * 1024 + n] = acc[ms][ns][r] + bias;
            }
        }
    }
}

// ---------------------------------------------------------------------------
// Flash attention v9 (round-9 proven: 49.8us): counted-vmcnt double-barrier
// main loop + psum via ones-row MFMA. 64 q/block, 4 waves 32q x 32k each;
// XCD-grouped heads; in-register P via cvt_pk + permlane; LDS 32KB.
// ---------------------------------------------------------------------------
__global__ __launch_bounds__(256, 4) void attn(
    const ushort_t* __restrict__ q, const ushort_t* __restrict__ k,
    const ushort_t* __restrict__ vT, ushort_t* __restrict__ o)
{
    __shared__ alignas(16) ushort_t ks[2][64 * 64];   // swizzled [key][d]   16KB
    __shared__ alignas(16) ushort_t vs[2][64 * 64];   // swizzled [vd][key]  16KB

    const int tid = threadIdx.x;
    const int w = tid >> 6, lane = tid & 63;
    const int quad = lane >> 4, lc = lane & 15;
    const int cs = lc & 7;               // row&7 for frag-read rows
    const int qsub = w & 1, ksub = w >> 1;

    // XCD-aware remap: dispatch round-robins linear id % 8 across XCDs.
    // Give XCD x the 4 heads bh = 4x..4x+3 (K/V 2MB, fits 4MB L2).
    const int id = blockIdx.y * 32 + blockIdx.x;     // 0..1023
    const int qt = (id >> 3) & 31;                   // q-tile 0..31
    const int bh = (id & 7) * 4 + (id >> 8);         // head 0..31 (bijective)

    // hoisted Q B-frags: B[k=d=quad*8+j][n=q=lc]; wave covers q = qsub*32 + j*16 + lc
    s16x8 aq[2][2];
    const ushort_t* qb = q + ((size_t)bh * T + qt * 64 + qsub * 32) * D;
#pragma unroll
    for (int j = 0; j < 2; j++)
#pragma unroll
        for (int h = 0; h < 2; h++)
            aq[j][h] = *(const s16x8*)(qb + (size_t)(j * 16 + lc) * D + h * 32 + quad * 8);

    // all-ones bf16 A-frag for the psum row-sum MFMA
    union { s16x8 v; ushort_t u[8]; } ones;
#pragma unroll
    for (int i = 0; i < 8; i++) ones.u[i] = 0x3F80;   // bf16 1.0

    fv4 accO[2][4] = {};   // accO[j][t4v] : [vd=quad*4+r][q=lc], partial over this wave's keys
    fv4 accPS[2] = {};     // row-sum accumulator: accPS[j][*] = sum_k P[k][q=lc]

    const ushort_t* kb0 = k + (size_t)bh * T * D;
    const ushort_t* vb0 = vT + (size_t)bh * D * T;

    // staging lane map: per GLDS inst, 8 rows x 8 chunks, chunk c^(r&7) swizzle
    const int sr8 = lane >> 3;                 // row within 8-row group
    const int sch = (lane & 7) ^ sr8;          // global chunk this lane fetches

    auto stage = [&](int kt, int buf) {
#pragma unroll
        for (int i = 0; i < 2; i++) {
            const int r = w * 16 + i * 8 + sr8;      // tile row 0..63
            GLDS(kb0 + (size_t)(kt * 64 + r) * 64 + sch * 8,
                 ks[buf] + (w * 16 + i * 8) * 64);
            GLDS(vb0 + (size_t)r * T + kt * 64 + sch * 8,
                 vs[buf] + (w * 16 + i * 8) * 64);
        }
    };

    stage(0, 0);   // 4 GLDS per wave

    for (int kt = 0; kt < T / 64; kt++) {
        const int cur = kt & 1;
        if (kt + 1 < T / 64) {
            stage(kt + 1, cur ^ 1);   // 4 more in flight
            // wait only tile kt's 4 loads (issued a full iteration ago);
            // tile kt+1's 4 loads STAY IN FLIGHT across the barrier (T4).
            asm volatile("s_waitcnt vmcnt(4)" ::: "memory");
        } else {
            asm volatile("s_waitcnt vmcnt(0)" ::: "memory");
        }
        __builtin_amdgcn_s_barrier();            // tile kt visible to all waves
        __builtin_amdgcn_sched_barrier(0);       // pin: no hoist above barrier

        // S^T = K @ Q^T over this wave's 32 keys: accST[j][t4k]
        fv4 accST[2][2] = {};
        __builtin_amdgcn_s_setprio(1);
#pragma unroll
        for (int t4k = 0; t4k < 2; t4k++) {
            const int row = ksub * 32 + t4k * 16 + lc;
            s16x8 ak0 = *(const s16x8*)(ks[cur] + row * 64 + ((quad ^ cs) << 3));
            s16x8 ak1 = *(const s16x8*)(ks[cur] + row * 64 + (((quad + 4) ^ cs) << 3));
#pragma unroll
            for (int j = 0; j < 2; j++) {
                accST[j][t4k] = __builtin_amdgcn_mfma_f32_16x16x32_bf16(
                    ak0, aq[j][0], accST[j][t4k], 0, 0, 0);
                accST[j][t4k] = __builtin_amdgcn_mfma_f32_16x16x32_bf16(
                    ak1, aq[j][1], accST[j][t4k], 0, 0, 0);
            }
        }
        __builtin_amdgcn_s_setprio(0);

        // hoist V^T A-frags (shared across j)
        s16x8 av[4];
#pragma unroll
        for (int t4v = 0; t4v < 4; t4v++) {
            const int row = t4v * 16 + lc;
            av[t4v] = *(const s16x8*)(vs[cur] + row * 64 + (((ksub * 4 + quad) ^ cs) << 3));
        }

        // per j: exp2 -> in-register bf16 pack -> quad-transpose -> PV (+psum MFMA)
#pragma unroll
        for (int j = 0; j < 2; j++) {
            float p0 = __builtin_amdgcn_exp2f(accST[j][0][0]);
            float p1 = __builtin_amdgcn_exp2f(accST[j][0][1]);
            float p2 = __builtin_amdgcn_exp2f(accST[j][0][2]);
            float p3 = __builtin_amdgcn_exp2f(accST[j][0][3]);
            float p4 = __builtin_amdgcn_exp2f(accST[j][1][0]);
            float p5 = __builtin_amdgcn_exp2f(accST[j][1][1]);
            float p6 = __builtin_amdgcn_exp2f(accST[j][1][2]);
            float p7 = __builtin_amdgcn_exp2f(accST[j][1][3]);

            int W00 = cvt_pk_bf16(p0, p1);   // keys q'*4+0,1   (t4k=0)
            int W01 = cvt_pk_bf16(p2, p3);   // keys q'*4+2,3   (t4k=0)
            int W10 = cvt_pk_bf16(p4, p5);   // keys 16+q'*4+0,1
            int W11 = cvt_pk_bf16(p6, p7);   // keys 16+q'*4+2,3
            // quad-transpose: after these, W00=pb0, W10=pb2, W01=pb1, W11=pb3
            asm("v_permlane32_swap_b32 %0, %1" : "+v"(W00), "+v"(W10));
            asm("v_permlane16_swap_b32 %0, %1" : "+v"(W00), "+v"(W10));
            asm("v_permlane32_swap_b32 %0, %1" : "+v"(W01), "+v"(W11));
            asm("v_permlane16_swap_b32 %0, %1" : "+v"(W01), "+v"(W11));

            union { int i[4]; s16x8 v; } pbu;
            pbu.i[0] = W00; pbu.i[1] = W01; pbu.i[2] = W10; pbu.i[3] = W11;

            __builtin_amdgcn_s_setprio(1);
#pragma unroll
            for (int t4v = 0; t4v < 4; t4v++)
                accO[j][t4v] = __builtin_amdgcn_mfma_f32_16x16x32_bf16(
                    av[t4v], pbu.v, accO[j][t4v], 0, 0, 0);
            // psum on the MFMA pipe: every output row = sum over 32 keys
            accPS[j] = __builtin_amdgcn_mfma_f32_16x16x32_bf16(
                ones.v, pbu.v, accPS[j], 0, 0, 0);
            __builtin_amdgcn_s_setprio(0);
        }

        __builtin_amdgcn_s_barrier();   // all reads of buf done before next stage
    }

    // psum per lane (replicated across quads by the ones-MFMA)
    float psum[2] = { accPS[0][0], accPS[1][0] };

    // ---- cross-wave (ksub) reduction via LDS scratch (aliases dead ks) ----
    float* sc = (float*)&ks[0][0];     // 4KB used; ks dead after loop
#pragma unroll
    for (int c = 0; c < 4; c++) {
        const int j = c >> 1, tv = (c & 1) * 2;
        __syncthreads();
        if (ksub == 1) {
            *(fv4*)(sc + ((qsub * 64 + lane) * 8))     = accO[j][tv];
            *(fv4*)(sc + ((qsub * 64 + lane) * 8 + 4)) = accO[j][tv + 1];
        }
        __syncthreads();
        if (ksub == 0) {
            accO[j][tv]     += *(fv4*)(sc + ((qsub * 64 + lane) * 8));
            accO[j][tv + 1] += *(fv4*)(sc + ((qsub * 64 + lane) * 8 + 4));
        }
    }
    __syncthreads();
    if (ksub == 1) {
        sc[(qsub * 64 + lane) * 2]     = psum[0];
        sc[(qsub * 64 + lane) * 2 + 1] = psum[1];
    }
    __syncthreads();
    if (ksub == 0) {
        psum[0] += sc[(qsub * 64 + lane) * 2];
        psum[1] += sc[(qsub * 64 + lane) * 2 + 1];

        // epilogue: normalize, write (B, T, H*64) bf16. Lane owns one q-row.
        const int b_ = bh >> 4, h_ = bh & 15;
#pragma unroll
        for (int j = 0; j < 2; j++) {
            float inv = 1.0f / psum[j];
            int row = qt * 64 + qsub * 32 + j * 16 + lc;
            ushort_t* op = o + ((size_t)b_ * T + row) * C + h_ * 64;
#pragma unroll
            for (int t4v = 0; t4v < 4; t4v++) {
                union { s16x4 v; int i[2]; } u;
                u.i[0] = cvt_pk_bf16(accO[j][t4v][0] * inv, accO[j][t4v][1] * inv);
                u.i[1] = cvt_pk_bf16(accO[j][t4v][2] * inv, accO[j][t4v][3] * inv);
                *(s16x4*)(op + t4v * 16 + quad * 4) = u.v;
            }
        }
    }
}

// ---------------------------------------------------------------------------
extern "C" void kernel_launch(void* const* d_in, const int* in_sizes, int n_in,
                              void* d_out, int out_size, void* d_ws, size_t ws_size,
                              hipStream_t stream)
{
    const float* Q  = (const float*)d_in[0];
    const float* K  = (const float*)d_in[1];
    const float* V  = (const float*)d_in[2];
    const float* Wq = (const float*)d_in[3];
    const float* bq = (const float*)d_in[4];
    const float* Wk = (const float*)d_in[5];
    const float* bk = (const float*)d_in[6];
    const float* Wv = (const float*)d_in[7];
    const float* bv = (const float*)d_in[8];
    const float* Wo = (const float*)d_in[9];
    const float* bo = (const float*)d_in[10];
    float* out = (float*)d_out;

    // ws: ow 24MB region | Wt 8 | qw 8 | kw 8 | vt 8
    ushort_t* ow = (ushort_t*)d_ws;
    ushort_t* Wt = ow + (size_t)3 * M * C;
    ushort_t* qw = Wt + (size_t)4096 * 1024;
    ushort_t* kw = qw + (size_t)M * C;
    ushort_t* vt = kw + (size_t)M * C;
    ushort_t* Wot = Wt + (size_t)3072 * 1024;

    dim3 blk(256);
    prep<<<dim3(1024), blk, 0, stream>>>(Wq, Wk, Wv, Wo, Wt);
    gemm_qkv<<<dim3(24, 32), blk, 0, stream>>>(Q, K, V, Wt, bq, bk, bv, qw, kw, vt);
    attn<<<dim3(T / 64, B * H), blk, 0, stream>>>(qw, kw, vt, ow);
    gemm_final<<<dim3(16, 32), blk, 0, stream>>>(ow, Wot, bo, out);
}

// Round 11
// 217.011 us; speedup vs baseline: 1.0127x; 1.0127x over previous
//
#include <hip/hip_runtime.h>
#include <hip/hip_bf16.h>
#include <math.h>

constexpr int B = 2, T = 2048, C = 1024, H = 16, D = 64;
constexpr int M = B * T;          // 4096
// 1/sqrt(64) * log2(e): scores premultiplied so softmax uses exp2 (1 VALU op)
constexpr float SCALE_L2E = 0.125f * 1.4426950408889634f;

typedef __attribute__((ext_vector_type(8))) short s16x8;  // 8 bf16 = 4 VGPRs
typedef __attribute__((ext_vector_type(4))) short s16x4;
typedef __attribute__((ext_vector_type(4))) float fv4;

typedef unsigned short ushort_t;

// cheap RNE fp32->bf16 (no NaN path; inputs are never NaN here).
static __device__ __forceinline__ ushort_t f2bf(float x) {
    union { float f; unsigned u; } c; c.f = x;
    unsigned u = c.u + 0x7FFFu + ((c.u >> 16) & 1u);
    return (ushort_t)(u >> 16);
}

// packed RNE fp32x2 -> bf16x2 (single VALU op; same rounding as f2bf)
static __device__ __forceinline__ int cvt_pk_bf16(float lo, float hi) {
    int r;
    asm("v_cvt_pk_bf16_f32 %0, %1, %2" : "=v"(r) : "v"(lo), "v"(hi));
    return r;
}

// global->LDS async copy, 16B per lane. LDS dest is WAVE-UNIFORM base +
// lane*16B (m104/m108) — pass a wave-uniform lp!
#define GLDS(gp, lp) __builtin_amdgcn_global_load_lds( \
    (const __attribute__((address_space(1))) void*)(gp), \
    (__attribute__((address_space(3))) void*)(lp), 16, 0, 0)

// ---------------------------------------------------------------------------
// prep: fused {fp32->bf16 convert of Q,K,V} + {transpose+convert of W's}.
// blocks [0,6144): convert; blocks [6144,7168): transpose (s = idx>>8).
// (round-9 proven version; the convert-fusion alternative lost 3x)
// ---------------------------------------------------------------------------
__global__ __launch_bounds__(256) void prep(
    const float* __restrict__ Q, const float* __restrict__ K,
    const float* __restrict__ V,
    const float* __restrict__ W0, const float* __restrict__ W1,
    const float* __restrict__ W2, const float* __restrict__ W3,
    ushort_t* __restrict__ dst, ushort_t* __restrict__ Wt)
{
    __shared__ ushort_t tile[64][72];
    const int tid = threadIdx.x;

    if (blockIdx.x < 6144) {
        // ---- convert path ----
        size_t e = ((size_t)blockIdx.x * 256 + tid) * 8;
        const float* src;
        size_t base;
        if (e < (size_t)M * C)          { src = Q; base = 0; }
        else if (e < 2 * (size_t)M * C) { src = K; base = (size_t)M * C; }
        else                            { src = V; base = 2 * (size_t)M * C; }
        const float* p = src + (e - base);
        float4 a = *(const float4*)p;
        float4 b = *(const float4*)(p + 4);
        union { s16x8 v; int i[4]; } o;
        o.i[0] = cvt_pk_bf16(a.x, a.y);
        o.i[1] = cvt_pk_bf16(a.z, a.w);
        o.i[2] = cvt_pk_bf16(b.x, b.y);
        o.i[3] = cvt_pk_bf16(b.z, b.w);
        *(s16x8*)(dst + e) = o.v;
        return;
    }

    // ---- weight transpose path ----
    const int idx = blockIdx.x - 6144;          // 0..1023
    const int s = idx >> 8;                     // 0..3
    const float* W = (s == 0) ? W0 : (s == 1) ? W1 : (s == 2) ? W2 : W3;
    const int k0 = (idx & 15) * 64, n0 = ((idx >> 4) & 15) * 64;
#pragma unroll
    for (int it = 0; it < 4; it++) {
        int f = it * 256 + tid;
        int r = f >> 4, c4 = (f & 15) * 4;
        float4 x = *(const float4*)(W + (size_t)(k0 + r) * C + n0 + c4);
        *(int*)&tile[r][c4]     = cvt_pk_bf16(x.x, x.y);
        *(int*)&tile[r][c4 + 2] = cvt_pk_bf16(x.z, x.w);
    }
    __syncthreads();
#pragma unroll
    for (int it = 0; it < 4; it++) {
        int f = it * 256 + tid;
        int rr = f >> 4, c4 = (f & 15) * 4;
        union { s16x4 v; ushort_t u[4]; } u;
#pragma unroll
        for (int j = 0; j < 4; j++) u.u[j] = tile[c4 + j][rr];
        *(s16x4*)(Wt + (size_t)(s * 1024 + n0 + rr) * 1024 + k0 + c4) = u.v;
    }
}

// ---------------------------------------------------------------------------
// Fused QKV projection GEMM (round-5 proven bf16 GLDS staging + XCD remap +
// LDS-transposed V epilogue), now with the counted-vmcnt double-barrier
// (attn-proven twice): prefetch's 4 GLDS stay in flight ACROSS the barrier;
// vmcnt(4) waits only the prior tile's loads.
// ---------------------------------------------------------------------------
__global__ __launch_bounds__(256) void gemm_qkv(
    const ushort_t* __restrict__ qkv, const ushort_t* __restrict__ Wt,
    const float* __restrict__ bq, const float* __restrict__ bk,
    const float* __restrict__ bv,
    ushort_t* __restrict__ qw, ushort_t* __restrict__ kw,
    ushort_t* __restrict__ vt)
{
    // As = sm[0..8192), Bs = sm[8192..16384); V-epilogue aliases sm as
    // a [128][136] transpose tile (17408 ushorts = 34KB).
    __shared__ alignas(16) ushort_t sm[17408];
    ushort_t* As0 = sm;
    ushort_t* Bs0 = sm + 8192;

    const int tid = threadIdx.x;
    const int w = tid >> 6, lane = tid & 63;
    const int quad = lane >> 4, lc = lane & 15;
    const int wm = w & 1, wn = w >> 1;

    // XCD-aware remap (dispatch round-robins lin%8 across XCDs)
    const int lin = blockIdx.y * 24 + blockIdx.x;    // 0..767
    const int xcd = lin % 8;
    const int i_ = lin / 8;                          // 0..95
    const int s = i_ >> 5;                           // 0,1,2
    const int r_ = i_ & 31;
    const int m0 = (xcd * 4 + (r_ >> 3)) * 128;
    const int nt = s * 8 + (r_ & 7);                 // 0..23
    const int nsec0 = (nt & 7) * 128;

    const ushort_t* Abase = qkv + (size_t)s * M * C;
    const ushort_t* Btbase = Wt + (size_t)nt * 128 * 1024;

    const int srow = (w << 4) + (lane >> 2);
    const int ske  = (lane & 3) * 8;

    fv4 acc[4][4] = {};

    auto stage = [&](int k0, int buf) {
#pragma unroll
        for (int i = 0; i < 2; i++) {
            int row = i * 64 + srow;
            GLDS(Abase + (size_t)(m0 + row) * 1024 + k0 + ske,
                 As0 + buf * 4096 + i * 2048 + w * 512);
            GLDS(Btbase + (size_t)row * 1024 + k0 + ske,
                 Bs0 + buf * 4096 + i * 2048 + w * 512);
        }
    };

    stage(0, 0);   // 4 GLDS per wave

    for (int kt = 0; kt < 32; kt++) {
        const int cur = kt & 1;
        if (kt + 1 < 32) {
            stage(kt * 32 + 32, cur ^ 1);   // 4 more in flight
            // wait only tile kt's 4 loads; tile kt+1's stay in flight (T4)
            asm volatile("s_waitcnt vmcnt(4)" ::: "memory");
        } else {
            asm volatile("s_waitcnt vmcnt(0)" ::: "memory");
        }
        __builtin_amdgcn_s_barrier();            // tile kt visible to all waves
        __builtin_amdgcn_sched_barrier(0);       // pin: no hoist above barrier

        s16x8 af[4], bf[4];
#pragma unroll
        for (int ms = 0; ms < 4; ms++)
            af[ms] = *(const s16x8*)(As0 + cur * 4096 + (wm * 64 + ms * 16 + lc) * 32 + quad * 8);
#pragma unroll
        for (int ns = 0; ns < 4; ns++)
            bf[ns] = *(const s16x8*)(Bs0 + cur * 4096 + (wn * 64 + ns * 16 + lc) * 32 + quad * 8);
#pragma unroll
        for (int ms = 0; ms < 4; ms++)
#pragma unroll
            for (int ns = 0; ns < 4; ns++)
                acc[ms][ns] = __builtin_amdgcn_mfma_f32_16x16x32_bf16(
                    af[ms], bf[ns], acc[ms][ns], 0, 0, 0);

        __builtin_amdgcn_s_barrier();   // reads of buf done before next stage
    }

    if (s == 2) {
        // V: transpose 128x128 tile through LDS, then coalesced vt stores.
        ushort_t* tp = sm;                 // [128 n][136 m], 34KB
#pragma unroll
        for (int ns = 0; ns < 4; ns++) {
            const int nl = wn * 64 + ns * 16 + lc;
            const float bias = bv[nsec0 + nl];
#pragma unroll
            for (int ms = 0; ms < 4; ms++) {
                const int ml = wm * 64 + ms * 16 + quad * 4;
                union { s16x4 v; int i2[2]; } u;
                u.i2[0] = cvt_pk_bf16(acc[ms][ns][0] + bias, acc[ms][ns][1] + bias);
                u.i2[1] = cvt_pk_bf16(acc[ms][ns][2] + bias, acc[ms][ns][3] + bias);
                *(s16x4*)&tp[nl * 136 + ml] = u.v;
            }
        }
        __syncthreads();
        const int b_ = m0 >> 11, t0 = m0 & 2047;
        // 128 n-rows x 128 m-cols: 8 iters x 256 threads x 8 elems = 16384
#pragma unroll
        for (int it = 0; it < 8; it++) {
            const int row = it * 16 + (tid >> 4);    // n-local 0..127
            const int ch = tid & 15;                 // m chunk 0..15
            const int n = nsec0 + row;
            const int h_ = n >> 6, d_ = n & 63;
            s16x8 v8 = *(const s16x8*)&tp[row * 136 + ch * 8];
            *(s16x8*)(vt + ((size_t)(b_ * H + h_) * 64 + d_) * T + t0 + ch * 8) = v8;
        }
        return;
    }

    const float* biasp = (s == 0) ? bq : bk;
    const float premul = (s == 0) ? SCALE_L2E : 1.0f;
    ushort_t* outp = (s == 0) ? qw : kw;

#pragma unroll
    for (int ns = 0; ns < 4; ns++) {
        const int nl = nsec0 + wn * 64 + ns * 16 + lc;
        const float bias = biasp[nl];
        const int h_ = nl >> 6, d_ = nl & 63;
#pragma unroll
        for (int ms = 0; ms < 4; ms++) {
#pragma unroll
            for (int r = 0; r < 4; r++) {
                int m = m0 + wm * 64 + ms * 16 + quad * 4 + r;
                float val = (acc[ms][ns][r] + bias) * premul;
                int b_ = m >> 11, t_ = m & (T - 1);
                size_t bh = (size_t)(b_ * H + h_);
                outp[((bh * T + t_) << 6) + d_] = f2bf(val);
            }
        }
    }
}

// ---------------------------------------------------------------------------
// Final projection: out = o(4096x1024)bf16 @ Wot^T + bo, fp32 out.
// BK=64 + chunk^(row&7) swizzled 128B-row LDS + counted-vmcnt double-barrier
// (round-10 version, refcheck'd). XCD-aware remap. LDS 48KB.
// ---------------------------------------------------------------------------
__global__ __launch_bounds__(256) void gemm_final(
    const ushort_t* __restrict__ A, const ushort_t* __restrict__ Wot,
    const float* __restrict__ bo, float* __restrict__ out)
{
    __shared__ alignas(16) ushort_t As[2][128 * 64];   // 32KB, rows 128B
    __shared__ alignas(16) ushort_t Bs[2][64 * 64];    // 16KB, rows 128B

    const int tid = threadIdx.x;
    const int w = tid >> 6, lane = tid & 63;
    const int quad = lane >> 4, lc = lane & 15;
    const int wm = w & 1, wn = w >> 1;
    const int c7 = lc & 7;

    const int lin = blockIdx.y * 16 + blockIdx.x;    // 0..511
    const int xcd = lin & 7;
    const int i_ = lin >> 3;                         // 0..63
    const int m0 = (xcd * 4 + (i_ >> 4)) * 128;
    const int n0 = (i_ & 15) * 64;

    // staging lane map: 8 rows x 8 chunks per GLDS; fetch chunk (lane&7)^r8
    const int r8 = lane >> 3;                  // row within 8-row group
    const int sch = (lane & 7) ^ r8;           // pre-swizzled global chunk

    fv4 acc[4][2] = {};

    auto stage = [&](int k0, int buf) {
#pragma unroll
        for (int i = 0; i < 4; i++) {          // A: wave w owns rows [w*32, w*32+32)
            int row = w * 32 + i * 8 + r8;
            GLDS(A + (size_t)(m0 + row) * 1024 + k0 + sch * 8,
                 As[buf] + (w * 32 + i * 8) * 64);
        }
#pragma unroll
        for (int i = 0; i < 2; i++) {          // B: wave w owns rows [w*16, w*16+16)
            int row = w * 16 + i * 8 + r8;
            GLDS(Wot + (size_t)(n0 + row) * 1024 + k0 + sch * 8,
                 Bs[buf] + (w * 16 + i * 8) * 64);
        }
    };

    stage(0, 0);   // 6 GLDS per wave

    for (int kt = 0; kt < 16; kt++) {
        const int cur = kt & 1;
        const int k0 = kt * 64;
        if (kt + 1 < 16) {
            stage(k0 + 64, cur ^ 1);
            asm volatile("s_waitcnt vmcnt(6)" ::: "memory");   // tile kt done
        } else {
            asm volatile("s_waitcnt vmcnt(0)" ::: "memory");
        }
        __builtin_amdgcn_s_barrier();
        __builtin_amdgcn_sched_barrier(0);

        s16x8 af[4][2], bf[2][2];
#pragma unroll
        for (int ms = 0; ms < 4; ms++) {
            const int row = wm * 64 + ms * 16 + lc;    // row&7 == lc&7
#pragma unroll
            for (int kh = 0; kh < 2; kh++)
                af[ms][kh] = *(const s16x8*)(As[cur] + row * 64
                                             + (((kh * 4 + quad) ^ c7) << 3));
        }
#pragma unroll
        for (int ns = 0; ns < 2; ns++) {
            const int row = wn * 32 + ns * 16 + lc;    // row&7 == lc&7
#pragma unroll
            for (int kh = 0; kh < 2; kh++)
                bf[ns][kh] = *(const s16x8*)(Bs[cur] + row * 64
                                             + (((kh * 4 + quad) ^ c7) << 3));
        }
#pragma unroll
        for (int ms = 0; ms < 4; ms++)
#pragma unroll
            for (int ns = 0; ns < 2; ns++)
#pragma unroll
                for (int kh = 0; kh < 2; kh++)
                    acc[ms][ns] = __builtin_amdgcn_mfma_f32_16x16x32_bf16(
                        af[ms][kh], bf[ns][kh], acc[ms][ns], 0, 0, 0);
        __builtin_amdgcn_s_barrier();
    }

#pragma unroll
    for (int ns = 0; ns < 2; ns++) {
        const int n = n0 + wn * 32 + ns * 16 + lc;
        const float bias = bo[n];
#pragma unroll
        for (int ms = 0; ms < 4; ms++) {
#pragma unroll
            for (int r = 0; r < 4; r++) {
                int m = m0 + wm * 64 + ms * 16 + quad * 4 + r;
                out[(size_t)m * 1024 + n] = acc[ms][ns][r] + bias;
            }
        }
    }
}

// ---------------------------------------------------------------------------
// Flash attention v9 (round-9 proven: 49.8us): counted-vmcnt double-barrier
// main loop + psum via ones-row MFMA. 64 q/block, 4 waves 32q x 32k each;
// XCD-grouped heads; in-register P via cvt_pk + permlane; LDS 32KB.
// ---------------------------------------------------------------------------
__global__ __launch_bounds__(256, 4) void attn(
    const ushort_t* __restrict__ q, const ushort_t* __restrict__ k,
    const ushort_t* __restrict__ vT, ushort_t* __restrict__ o)
{
    __shared__ alignas(16) ushort_t ks[2][64 * 64];   // swizzled [key][d]   16KB
    __shared__ alignas(16) ushort_t vs[2][64 * 64];   // swizzled [vd][key]  16KB

    const int tid = threadIdx.x;
    const int w = tid >> 6, lane = tid & 63;
    const int quad = lane >> 4, lc = lane & 15;
    const int cs = lc & 7;               // row&7 for frag-read rows
    const int qsub = w & 1, ksub = w >> 1;

    // XCD-aware remap: dispatch round-robins linear id % 8 across XCDs.
    // Give XCD x the 4 heads bh = 4x..4x+3 (K/V 2MB, fits 4MB L2).
    const int id = blockIdx.y * 32 + blockIdx.x;     // 0..1023
    const int qt = (id >> 3) & 31;                   // q-tile 0..31
    const int bh = (id & 7) * 4 + (id >> 8);         // head 0..31 (bijective)

    // hoisted Q B-frags: B[k=d=quad*8+j][n=q=lc]; wave covers q = qsub*32 + j*16 + lc
    s16x8 aq[2][2];
    const ushort_t* qb = q + ((size_t)bh * T + qt * 64 + qsub * 32) * D;
#pragma unroll
    for (int j = 0; j < 2; j++)
#pragma unroll
        for (int h = 0; h < 2; h++)
            aq[j][h] = *(const s16x8*)(qb + (size_t)(j * 16 + lc) * D + h * 32 + quad * 8);

    // all-ones bf16 A-frag for the psum row-sum MFMA
    union { s16x8 v; ushort_t u[8]; } ones;
#pragma unroll
    for (int i = 0; i < 8; i++) ones.u[i] = 0x3F80;   // bf16 1.0

    fv4 accO[2][4] = {};   // accO[j][t4v] : [vd=quad*4+r][q=lc], partial over this wave's keys
    fv4 accPS[2] = {};     // row-sum accumulator: accPS[j][*] = sum_k P[k][q=lc]

    const ushort_t* kb0 = k + (size_t)bh * T * D;
    const ushort_t* vb0 = vT + (size_t)bh * D * T;

    // staging lane map: per GLDS inst, 8 rows x 8 chunks, chunk c^(r&7) swizzle
    const int sr8 = lane >> 3;                 // row within 8-row group
    const int sch = (lane & 7) ^ sr8;          // global chunk this lane fetches

    auto stage = [&](int kt, int buf) {
#pragma unroll
        for (int i = 0; i < 2; i++) {
            const int r = w * 16 + i * 8 + sr8;      // tile row 0..63
            GLDS(kb0 + (size_t)(kt * 64 + r) * 64 + sch * 8,
                 ks[buf] + (w * 16 + i * 8) * 64);
            GLDS(vb0 + (size_t)r * T + kt * 64 + sch * 8,
                 vs[buf] + (w * 16 + i * 8) * 64);
        }
    };

    stage(0, 0);   // 4 GLDS per wave

    for (int kt = 0; kt < T / 64; kt++) {
        const int cur = kt & 1;
        if (kt + 1 < T / 64) {
            stage(kt + 1, cur ^ 1);   // 4 more in flight
            // wait only tile kt's 4 loads (issued a full iteration ago);
            // tile kt+1's 4 loads STAY IN FLIGHT across the barrier (T4).
            asm volatile("s_waitcnt vmcnt(4)" ::: "memory");
        } else {
            asm volatile("s_waitcnt vmcnt(0)" ::: "memory");
        }
        __builtin_amdgcn_s_barrier();            // tile kt visible to all waves
        __builtin_amdgcn_sched_barrier(0);       // pin: no hoist above barrier

        // S^T = K @ Q^T over this wave's 32 keys: accST[j][t4k]
        fv4 accST[2][2] = {};
        __builtin_amdgcn_s_setprio(1);
#pragma unroll
        for (int t4k = 0; t4k < 2; t4k++) {
            const int row = ksub * 32 + t4k * 16 + lc;
            s16x8 ak0 = *(const s16x8*)(ks[cur] + row * 64 + ((quad ^ cs) << 3));
            s16x8 ak1 = *(const s16x8*)(ks[cur] + row * 64 + (((quad + 4) ^ cs) << 3));
#pragma unroll
            for (int j = 0; j < 2; j++) {
                accST[j][t4k] = __builtin_amdgcn_mfma_f32_16x16x32_bf16(
                    ak0, aq[j][0], accST[j][t4k], 0, 0, 0);
                accST[j][t4k] = __builtin_amdgcn_mfma_f32_16x16x32_bf16(
                    ak1, aq[j][1], accST[j][t4k], 0, 0, 0);
            }
        }
        __builtin_amdgcn_s_setprio(0);

        // hoist V^T A-frags (shared across j)
        s16x8 av[4];
#pragma unroll
        for (int t4v = 0; t4v < 4; t4v++) {
            const int row = t4v * 16 + lc;
            av[t4v] = *(const s16x8*)(vs[cur] + row * 64 + (((ksub * 4 + quad) ^ cs) << 3));
        }

        // per j: exp2 -> in-register bf16 pack -> quad-transpose -> PV (+psum MFMA)
#pragma unroll
        for (int j = 0; j < 2; j++) {
            float p0 = __builtin_amdgcn_exp2f(accST[j][0][0]);
            float p1 = __builtin_amdgcn_exp2f(accST[j][0][1]);
            float p2 = __builtin_amdgcn_exp2f(accST[j][0][2]);
            float p3 = __builtin_amdgcn_exp2f(accST[j][0][3]);
            float p4 = __builtin_amdgcn_exp2f(accST[j][1][0]);
            float p5 = __builtin_amdgcn_exp2f(accST[j][1][1]);
            float p6 = __builtin_amdgcn_exp2f(accST[j][1][2]);
            float p7 = __builtin_amdgcn_exp2f(accST[j][1][3]);

            int W00 = cvt_pk_bf16(p0, p1);   // keys q'*4+0,1   (t4k=0)
            int W01 = cvt_pk_bf16(p2, p3);   // keys q'*4+2,3   (t4k=0)
            int W10 = cvt_pk_bf16(p4, p5);   // keys 16+q'*4+0,1
            int W11 = cvt_pk_bf16(p6, p7);   // keys 16+q'*4+2,3
            // quad-transpose: after these, W00=pb0, W10=pb2, W01=pb1, W11=pb3
            asm("v_permlane32_swap_b32 %0, %1" : "+v"(W00), "+v"(W10));
            asm("v_permlane16_swap_b32 %0, %1" : "+v"(W00), "+v"(W10));
            asm("v_permlane32_swap_b32 %0, %1" : "+v"(W01), "+v"(W11));
            asm("v_permlane16_swap_b32 %0, %1" : "+v"(W01), "+v"(W11));

            union { int i[4]; s16x8 v; } pbu;
            pbu.i[0] = W00; pbu.i[1] = W01; pbu.i[2] = W10; pbu.i[3] = W11;

            __builtin_amdgcn_s_setprio(1);
#pragma unroll
            for (int t4v = 0; t4v < 4; t4v++)
                accO[j][t4v] = __builtin_amdgcn_mfma_f32_16x16x32_bf16(
                    av[t4v], pbu.v, accO[j][t4v], 0, 0, 0);
            // psum on the MFMA pipe: every output row = sum over 32 keys
            accPS[j] = __builtin_amdgcn_mfma_f32_16x16x32_bf16(
                ones.v, pbu.v, accPS[j], 0, 0, 0);
            __builtin_amdgcn_s_setprio(0);
        }

        __builtin_amdgcn_s_barrier();   // all reads of buf done before next stage
    }

    // psum per lane (replicated across quads by the ones-MFMA)
    float psum[2] = { accPS[0][0], accPS[1][0] };

    // ---- cross-wave (ksub) reduction via LDS scratch (aliases dead ks) ----
    float* sc = (float*)&ks[0][0];     // 4KB used; ks dead after loop
#pragma unroll
    for (int c = 0; c < 4; c++) {
        const int j = c >> 1, tv = (c & 1) * 2;
        __syncthreads();
        if (ksub == 1) {
            *(fv4*)(sc + ((qsub * 64 + lane) * 8))     = accO[j][tv];
            *(fv4*)(sc + ((qsub * 64 + lane) * 8 + 4)) = accO[j][tv + 1];
        }
        __syncthreads();
        if (ksub == 0) {
            accO[j][tv]     += *(fv4*)(sc + ((qsub * 64 + lane) * 8));
            accO[j][tv + 1] += *(fv4*)(sc + ((qsub * 64 + lane) * 8 + 4));
        }
    }
    __syncthreads();
    if (ksub == 1) {
        sc[(qsub * 64 + lane) * 2]     = psum[0];
        sc[(qsub * 64 + lane) * 2 + 1] = psum[1];
    }
    __syncthreads();
    if (ksub == 0) {
        psum[0] += sc[(qsub * 64 + lane) * 2];
        psum[1] += sc[(qsub * 64 + lane) * 2 + 1];

        // epilogue: normalize, write (B, T, H*64) bf16. Lane owns one q-row.
        const int b_ = bh >> 4, h_ = bh & 15;
#pragma unroll
        for (int j = 0; j < 2; j++) {
            float inv = 1.0f / psum[j];
            int row = qt * 64 + qsub * 32 + j * 16 + lc;
            ushort_t* op = o + ((size_t)b_ * T + row) * C + h_ * 64;
#pragma unroll
            for (int t4v = 0; t4v < 4; t4v++) {
                union { s16x4 v; int i[2]; } u;
                u.i[0] = cvt_pk_bf16(accO[j][t4v][0] * inv, accO[j][t4v][1] * inv);
                u.i[1] = cvt_pk_bf16(accO[j][t4v][2] * inv, accO[j][t4v][3] * inv);
                *(s16x4*)(op + t4v * 16 + quad * 4) = u.v;
            }
        }
    }
}

// ---------------------------------------------------------------------------
extern "C" void kernel_launch(void* const* d_in, const int* in_sizes, int n_in,
                              void* d_out, int out_size, void* d_ws, size_t ws_size,
                              hipStream_t stream)
{
    const float* Q  = (const float*)d_in[0];
    const float* K  = (const float*)d_in[1];
    const float* V  = (const float*)d_in[2];
    const float* Wq = (const float*)d_in[3];
    const float* bq = (const float*)d_in[4];
    const float* Wk = (const float*)d_in[5];
    const float* bk = (const float*)d_in[6];
    const float* Wv = (const float*)d_in[7];
    const float* bv = (const float*)d_in[8];
    const float* Wo = (const float*)d_in[9];
    const float* bo = (const float*)d_in[10];
    float* out = (float*)d_out;

    // ws: qkvbf 24MB (aliased as ow after gemm_qkv) | Wt 8 | qw 8 | kw 8 | vt 8
    ushort_t* qkvbf = (ushort_t*)d_ws;
    ushort_t* Wt = qkvbf + (size_t)3 * M * C;
    ushort_t* qw = Wt + (size_t)4096 * 1024;
    ushort_t* kw = qw + (size_t)M * C;
    ushort_t* vt = kw + (size_t)M * C;
    ushort_t* ow = qkvbf;                      // alias: qkv bf16 dead after gemm_qkv
    ushort_t* Wot = Wt + (size_t)3072 * 1024;

    dim3 blk(256);
    prep<<<dim3(7168), blk, 0, stream>>>(Q, K, V, Wq, Wk, Wv, Wo, qkvbf, Wt);
    gemm_qkv<<<dim3(24, 32), blk, 0, stream>>>(qkvbf, Wt, bq, bk, bv, qw, kw, vt);
    attn<<<dim3(T / 64, B * H), blk, 0, stream>>>(qw, kw, vt, ow);
    gemm_final<<<dim3(16, 32), blk, 0, stream>>>(ow, Wot, bo, out);
}

// Round 12
// 215.555 us; speedup vs baseline: 1.0196x; 1.0068x over previous
//
#include <hip/hip_runtime.h>
#include <hip/hip_bf16.h>
#include <math.h>

constexpr int B = 2, T = 2048, C = 1024, H = 16, D = 64;
constexpr int M = B * T;          // 4096
// 1/sqrt(64) * log2(e): scores premultiplied so softmax uses exp2 (1 VALU op)
constexpr float SCALE_L2E = 0.125f * 1.4426950408889634f;

typedef __attribute__((ext_vector_type(8))) short s16x8;  // 8 bf16 = 4 VGPRs
typedef __attribute__((ext_vector_type(4))) short s16x4;
typedef __attribute__((ext_vector_type(4))) float fv4;

typedef unsigned short ushort_t;

// cheap RNE fp32->bf16 (no NaN path; inputs are never NaN here).
static __device__ __forceinline__ ushort_t f2bf(float x) {
    union { float f; unsigned u; } c; c.f = x;
    unsigned u = c.u + 0x7FFFu + ((c.u >> 16) & 1u);
    return (ushort_t)(u >> 16);
}

// packed RNE fp32x2 -> bf16x2 (single VALU op; same rounding as f2bf)
static __device__ __forceinline__ int cvt_pk_bf16(float lo, float hi) {
    int r;
    asm("v_cvt_pk_bf16_f32 %0, %1, %2" : "=v"(r) : "v"(lo), "v"(hi));
    return r;
}

// global->LDS async copy, 16B per lane. LDS dest is WAVE-UNIFORM base +
// lane*16B (m104/m108) — pass a wave-uniform lp!
#define GLDS(gp, lp) __builtin_amdgcn_global_load_lds( \
    (const __attribute__((address_space(1))) void*)(gp), \
    (__attribute__((address_space(3))) void*)(lp), 16, 0, 0)

// ---------------------------------------------------------------------------
// prep: fused {fp32->bf16 convert of Q,K,V} + {transpose+convert of W's}.
// blocks [0,6144): convert; blocks [6144,7168): transpose (s = idx>>8).
// ---------------------------------------------------------------------------
__global__ __launch_bounds__(256) void prep(
    const float* __restrict__ Q, const float* __restrict__ K,
    const float* __restrict__ V,
    const float* __restrict__ W0, const float* __restrict__ W1,
    const float* __restrict__ W2, const float* __restrict__ W3,
    ushort_t* __restrict__ dst, ushort_t* __restrict__ Wt)
{
    __shared__ ushort_t tile[64][72];
    const int tid = threadIdx.x;

    if (blockIdx.x < 6144) {
        // ---- convert path ----
        size_t e = ((size_t)blockIdx.x * 256 + tid) * 8;
        const float* src;
        size_t base;
        if (e < (size_t)M * C)          { src = Q; base = 0; }
        else if (e < 2 * (size_t)M * C) { src = K; base = (size_t)M * C; }
        else                            { src = V; base = 2 * (size_t)M * C; }
        const float* p = src + (e - base);
        float4 a = *(const float4*)p;
        float4 b = *(const float4*)(p + 4);
        union { s16x8 v; int i[4]; } o;
        o.i[0] = cvt_pk_bf16(a.x, a.y);
        o.i[1] = cvt_pk_bf16(a.z, a.w);
        o.i[2] = cvt_pk_bf16(b.x, b.y);
        o.i[3] = cvt_pk_bf16(b.z, b.w);
        *(s16x8*)(dst + e) = o.v;
        return;
    }

    // ---- weight transpose path ----
    const int idx = blockIdx.x - 6144;          // 0..1023
    const int s = idx >> 8;                     // 0..3
    const float* W = (s == 0) ? W0 : (s == 1) ? W1 : (s == 2) ? W2 : W3;
    const int k0 = (idx & 15) * 64, n0 = ((idx >> 4) & 15) * 64;
#pragma unroll
    for (int it = 0; it < 4; it++) {
        int f = it * 256 + tid;
        int r = f >> 4, c4 = (f & 15) * 4;
        float4 x = *(const float4*)(W + (size_t)(k0 + r) * C + n0 + c4);
        *(int*)&tile[r][c4]     = cvt_pk_bf16(x.x, x.y);
        *(int*)&tile[r][c4 + 2] = cvt_pk_bf16(x.z, x.w);
    }
    __syncthreads();
#pragma unroll
    for (int it = 0; it < 4; it++) {
        int f = it * 256 + tid;
        int rr = f >> 4, c4 = (f & 15) * 4;
        union { s16x4 v; ushort_t u[4]; } u;
#pragma unroll
        for (int j = 0; j < 4; j++) u.u[j] = tile[c4 + j][rr];
        *(s16x4*)(Wt + (size_t)(s * 1024 + n0 + rr) * 1024 + k0 + c4) = u.v;
    }
}

// ---------------------------------------------------------------------------
// Fused QKV projection GEMM (round-5 proven bf16 GLDS staging + XCD remap +
// LDS-transposed V epilogue) with counted-vmcnt double-barrier.
// ---------------------------------------------------------------------------
__global__ __launch_bounds__(256) void gemm_qkv(
    const ushort_t* __restrict__ qkv, const ushort_t* __restrict__ Wt,
    const float* __restrict__ bq, const float* __restrict__ bk,
    const float* __restrict__ bv,
    ushort_t* __restrict__ qw, ushort_t* __restrict__ kw,
    ushort_t* __restrict__ vt)
{
    // As = sm[0..8192), Bs = sm[8192..16384); V-epilogue aliases sm as
    // a [128][136] transpose tile (17408 ushorts = 34KB).
    __shared__ alignas(16) ushort_t sm[17408];
    ushort_t* As0 = sm;
    ushort_t* Bs0 = sm + 8192;

    const int tid = threadIdx.x;
    const int w = tid >> 6, lane = tid & 63;
    const int quad = lane >> 4, lc = lane & 15;
    const int wm = w & 1, wn = w >> 1;

    // XCD-aware remap (dispatch round-robins lin%8 across XCDs)
    const int lin = blockIdx.y * 24 + blockIdx.x;    // 0..767
    const int xcd = lin % 8;
    const int i_ = lin / 8;                          // 0..95
    const int s = i_ >> 5;                           // 0,1,2
    const int r_ = i_ & 31;
    const int m0 = (xcd * 4 + (r_ >> 3)) * 128;
    const int nt = s * 8 + (r_ & 7);                 // 0..23
    const int nsec0 = (nt & 7) * 128;

    const ushort_t* Abase = qkv + (size_t)s * M * C;
    const ushort_t* Btbase = Wt + (size_t)nt * 128 * 1024;

    const int srow = (w << 4) + (lane >> 2);
    const int ske  = (lane & 3) * 8;

    fv4 acc[4][4] = {};

    auto stage = [&](int k0, int buf) {
#pragma unroll
        for (int i = 0; i < 2; i++) {
            int row = i * 64 + srow;
            GLDS(Abase + (size_t)(m0 + row) * 1024 + k0 + ske,
                 As0 + buf * 4096 + i * 2048 + w * 512);
            GLDS(Btbase + (size_t)row * 1024 + k0 + ske,
                 Bs0 + buf * 4096 + i * 2048 + w * 512);
        }
    };

    stage(0, 0);   // 4 GLDS per wave

    for (int kt = 0; kt < 32; kt++) {
        const int cur = kt & 1;
        if (kt + 1 < 32) {
            stage(kt * 32 + 32, cur ^ 1);   // 4 more in flight
            // wait only tile kt's 4 loads; tile kt+1's stay in flight (T4)
            asm volatile("s_waitcnt vmcnt(4)" ::: "memory");
        } else {
            asm volatile("s_waitcnt vmcnt(0)" ::: "memory");
        }
        __builtin_amdgcn_s_barrier();            // tile kt visible to all waves
        __builtin_amdgcn_sched_barrier(0);       // pin: no hoist above barrier

        s16x8 af[4], bf[4];
#pragma unroll
        for (int ms = 0; ms < 4; ms++)
            af[ms] = *(const s16x8*)(As0 + cur * 4096 + (wm * 64 + ms * 16 + lc) * 32 + quad * 8);
#pragma unroll
        for (int ns = 0; ns < 4; ns++)
            bf[ns] = *(const s16x8*)(Bs0 + cur * 4096 + (wn * 64 + ns * 16 + lc) * 32 + quad * 8);
#pragma unroll
        for (int ms = 0; ms < 4; ms++)
#pragma unroll
            for (int ns = 0; ns < 4; ns++)
                acc[ms][ns] = __builtin_amdgcn_mfma_f32_16x16x32_bf16(
                    af[ms], bf[ns], acc[ms][ns], 0, 0, 0);

        __builtin_amdgcn_s_barrier();   // reads of buf done before next stage
    }

    if (s == 2) {
        // V: transpose 128x128 tile through LDS, then coalesced vt stores.
        ushort_t* tp = sm;                 // [128 n][136 m], 34KB
#pragma unroll
        for (int ns = 0; ns < 4; ns++) {
            const int nl = wn * 64 + ns * 16 + lc;
            const float bias = bv[nsec0 + nl];
#pragma unroll
            for (int ms = 0; ms < 4; ms++) {
                const int ml = wm * 64 + ms * 16 + quad * 4;
                union { s16x4 v; int i2[2]; } u;
                u.i2[0] = cvt_pk_bf16(acc[ms][ns][0] + bias, acc[ms][ns][1] + bias);
                u.i2[1] = cvt_pk_bf16(acc[ms][ns][2] + bias, acc[ms][ns][3] + bias);
                *(s16x4*)&tp[nl * 136 + ml] = u.v;
            }
        }
        __syncthreads();
        const int b_ = m0 >> 11, t0 = m0 & 2047;
        // 128 n-rows x 128 m-cols: 8 iters x 256 threads x 8 elems = 16384
#pragma unroll
        for (int it = 0; it < 8; it++) {
            const int row = it * 16 + (tid >> 4);    // n-local 0..127
            const int ch = tid & 15;                 // m chunk 0..15
            const int n = nsec0 + row;
            const int h_ = n >> 6, d_ = n & 63;
            s16x8 v8 = *(const s16x8*)&tp[row * 136 + ch * 8];
            *(s16x8*)(vt + ((size_t)(b_ * H + h_) * 64 + d_) * T + t0 + ch * 8) = v8;
        }
        return;
    }

    const float* biasp = (s == 0) ? bq : bk;
    const float premul = (s == 0) ? SCALE_L2E : 1.0f;
    ushort_t* outp = (s == 0) ? qw : kw;

#pragma unroll
    for (int ns = 0; ns < 4; ns++) {
        const int nl = nsec0 + wn * 64 + ns * 16 + lc;
        const float bias = biasp[nl];
        const int h_ = nl >> 6, d_ = nl & 63;
#pragma unroll
        for (int ms = 0; ms < 4; ms++) {
#pragma unroll
            for (int r = 0; r < 4; r++) {
                int m = m0 + wm * 64 + ms * 16 + quad * 4 + r;
                float val = (acc[ms][ns][r] + bias) * premul;
                int b_ = m >> 11, t_ = m & (T - 1);
                size_t bh = (size_t)(b_ * H + h_);
                outp[((bh * T + t_) << 6) + d_] = f2bf(val);
            }
        }
    }
}

// ---------------------------------------------------------------------------
// Final projection: out = o(4096x1024)bf16 @ Wot^T + bo, fp32 out.
// 64x64 tiles: grid 1024 blocks = 4 blocks/CU = 16 waves/CU (2x the old
// 128x64/512-block config — grid, not LDS, was the residency limit).
// BK=64, chunk^(row&7) swizzled 128B-row LDS, counted-vmcnt double-barrier.
// XCD remap: xcd 0..7 owns 8 m-tiles x 16 n-tiles (A 1MB + B 2MB L2-fit).
// LDS 32KB.
// ---------------------------------------------------------------------------
__global__ __launch_bounds__(256) void gemm_final(
    const ushort_t* __restrict__ A, const ushort_t* __restrict__ Wot,
    const float* __restrict__ bo, float* __restrict__ out)
{
    __shared__ alignas(16) ushort_t As[2][64 * 64];    // 16KB, rows 128B
    __shared__ alignas(16) ushort_t Bs[2][64 * 64];    // 16KB, rows 128B

    const int tid = threadIdx.x;
    const int w = tid >> 6, lane = tid & 63;
    const int quad = lane >> 4, lc = lane & 15;
    const int wm = w & 1, wn = w >> 1;
    const int c7 = lc & 7;

    const int lin = blockIdx.y * 16 + blockIdx.x;    // 0..1023
    const int xcd = lin & 7;
    const int i_ = lin >> 3;                         // 0..127
    const int m0 = (xcd * 8 + (i_ >> 4)) * 64;       // 64 m-tiles, bijective
    const int n0 = (i_ & 15) * 64;

    // staging lane map: 8 rows x 8 chunks per GLDS; fetch chunk (lane&7)^r8
    const int r8 = lane >> 3;                  // row within 8-row group
    const int sch = (lane & 7) ^ r8;           // pre-swizzled global chunk

    fv4 acc[2][2] = {};

    auto stage = [&](int k0, int buf) {
#pragma unroll
        for (int i = 0; i < 2; i++) {          // wave w owns rows [w*16, w*16+16)
            int row = w * 16 + i * 8 + r8;
            GLDS(A + (size_t)(m0 + row) * 1024 + k0 + sch * 8,
                 As[buf] + (w * 16 + i * 8) * 64);
            GLDS(Wot + (size_t)(n0 + row) * 1024 + k0 + sch * 8,
                 Bs[buf] + (w * 16 + i * 8) * 64);
        }
    };

    stage(0, 0);   // 4 GLDS per wave

    for (int kt = 0; kt < 16; kt++) {
        const int cur = kt & 1;
        const int k0 = kt * 64;
        if (kt + 1 < 16) {
            stage(k0 + 64, cur ^ 1);
            asm volatile("s_waitcnt vmcnt(4)" ::: "memory");   // tile kt done
        } else {
            asm volatile("s_waitcnt vmcnt(0)" ::: "memory");
        }
        __builtin_amdgcn_s_barrier();
        __builtin_amdgcn_sched_barrier(0);

        s16x8 af[2][2], bf[2][2];
#pragma unroll
        for (int ms = 0; ms < 2; ms++) {
            const int row = wm * 32 + ms * 16 + lc;    // row&7 == lc&7
#pragma unroll
            for (int kh = 0; kh < 2; kh++)
                af[ms][kh] = *(const s16x8*)(As[cur] + row * 64
                                             + (((kh * 4 + quad) ^ c7) << 3));
        }
#pragma unroll
        for (int ns = 0; ns < 2; ns++) {
            const int row = wn * 32 + ns * 16 + lc;    // row&7 == lc&7
#pragma unroll
            for (int kh = 0; kh < 2; kh++)
                bf[ns][kh] = *(const s16x8*)(Bs[cur] + row * 64
                                             + (((kh * 4 + quad) ^ c7) << 3));
        }
#pragma unroll
        for (int ms = 0; ms < 2; ms++)
#pragma unroll
            for (int ns = 0; ns < 2; ns++)
#pragma unroll
                for (int kh = 0; kh < 2; kh++)
                    acc[ms][ns] = __builtin_amdgcn_mfma_f32_16x16x32_bf16(
                        af[ms][kh], bf[ns][kh], acc[ms][ns], 0, 0, 0);
        __builtin_amdgcn_s_barrier();
    }

#pragma unroll
    for (int ns = 0; ns < 2; ns++) {
        const int n = n0 + wn * 32 + ns * 16 + lc;
        const float bias = bo[n];
#pragma unroll
        for (int ms = 0; ms < 2; ms++) {
#pragma unroll
            for (int r = 0; r < 4; r++) {
                int m = m0 + wm * 32 + ms * 16 + quad * 4 + r;
                out[(size_t)m * 1024 + n] = acc[ms][ns][r] + bias;
            }
        }
    }
}

// ---------------------------------------------------------------------------
// Flash attention v9 (round-9 proven: 49.8us): counted-vmcnt double-barrier
// main loop + psum via ones-row MFMA. 64 q/block, 4 waves 32q x 32k each;
// XCD-grouped heads; in-register P via cvt_pk + permlane; LDS 32KB.
// ---------------------------------------------------------------------------
__global__ __launch_bounds__(256, 4) void attn(
    const ushort_t* __restrict__ q, const ushort_t* __restrict__ k,
    const ushort_t* __restrict__ vT, ushort_t* __restrict__ o)
{
    __shared__ alignas(16) ushort_t ks[2][64 * 64];   // swizzled [key][d]   16KB
    __shared__ alignas(16) ushort_t vs[2][64 * 64];   // swizzled [vd][key]  16KB

    const int tid = threadIdx.x;
    const int w = tid >> 6, lane = tid & 63;
    const int quad = lane >> 4, lc = lane & 15;
    const int cs = lc & 7;               // row&7 for frag-read rows
    const int qsub = w & 1, ksub = w >> 1;

    // XCD-aware remap: dispatch round-robins linear id % 8 across XCDs.
    // Give XCD x the 4 heads bh = 4x..4x+3 (K/V 2MB, fits 4MB L2).
    const int id = blockIdx.y * 32 + blockIdx.x;     // 0..1023
    const int qt = (id >> 3) & 31;                   // q-tile 0..31
    const int bh = (id & 7) * 4 + (id >> 8);         // head 0..31 (bijective)

    // hoisted Q B-frags: B[k=d=quad*8+j][n=q=lc]; wave covers q = qsub*32 + j*16 + lc
    s16x8 aq[2][2];
    const ushort_t* qb = q + ((size_t)bh * T + qt * 64 + qsub * 32) * D;
#pragma unroll
    for (int j = 0; j < 2; j++)
#pragma unroll
        for (int h = 0; h < 2; h++)
            aq[j][h] = *(const s16x8*)(qb + (size_t)(j * 16 + lc) * D + h * 32 + quad * 8);

    // all-ones bf16 A-frag for the psum row-sum MFMA
    union { s16x8 v; ushort_t u[8]; } ones;
#pragma unroll
    for (int i = 0; i < 8; i++) ones.u[i] = 0x3F80;   // bf16 1.0

    fv4 accO[2][4] = {};   // accO[j][t4v] : [vd=quad*4+r][q=lc], partial over this wave's keys
    fv4 accPS[2] = {};     // row-sum accumulator: accPS[j][*] = sum_k P[k][q=lc]

    const ushort_t* kb0 = k + (size_t)bh * T * D;
    const ushort_t* vb0 = vT + (size_t)bh * D * T;

    // staging lane map: per GLDS inst, 8 rows x 8 chunks, chunk c^(r&7) swizzle
    const int sr8 = lane >> 3;                 // row within 8-row group
    const int sch = (lane & 7) ^ sr8;          // global chunk this lane fetches

    auto stage = [&](int kt, int buf) {
#pragma unroll
        for (int i = 0; i < 2; i++) {
            const int r = w * 16 + i * 8 + sr8;      // tile row 0..63
            GLDS(kb0 + (size_t)(kt * 64 + r) * 64 + sch * 8,
                 ks[buf] + (w * 16 + i * 8) * 64);
            GLDS(vb0 + (size_t)r * T + kt * 64 + sch * 8,
                 vs[buf] + (w * 16 + i * 8) * 64);
        }
    };

    stage(0, 0);   // 4 GLDS per wave

    for (int kt = 0; kt < T / 64; kt++) {
        const int cur = kt & 1;
        if (kt + 1 < T / 64) {
            stage(kt + 1, cur ^ 1);   // 4 more in flight
            // wait only tile kt's 4 loads (issued a full iteration ago);
            // tile kt+1's 4 loads STAY IN FLIGHT across the barrier (T4).
            asm volatile("s_waitcnt vmcnt(4)" ::: "memory");
        } else {
            asm volatile("s_waitcnt vmcnt(0)" ::: "memory");
        }
        __builtin_amdgcn_s_barrier();            // tile kt visible to all waves
        __builtin_amdgcn_sched_barrier(0);       // pin: no hoist above barrier

        // S^T = K @ Q^T over this wave's 32 keys: accST[j][t4k]
        fv4 accST[2][2] = {};
        __builtin_amdgcn_s_setprio(1);
#pragma unroll
        for (int t4k = 0; t4k < 2; t4k++) {
            const int row = ksub * 32 + t4k * 16 + lc;
            s16x8 ak0 = *(const s16x8*)(ks[cur] + row * 64 + ((quad ^ cs) << 3));
            s16x8 ak1 = *(const s16x8*)(ks[cur] + row * 64 + (((quad + 4) ^ cs) << 3));
#pragma unroll
            for (int j = 0; j < 2; j++) {
                accST[j][t4k] = __builtin_amdgcn_mfma_f32_16x16x32_bf16(
                    ak0, aq[j][0], accST[j][t4k], 0, 0, 0);
                accST[j][t4k] = __builtin_amdgcn_mfma_f32_16x16x32_bf16(
                    ak1, aq[j][1], accST[j][t4k], 0, 0, 0);
            }
        }
        __builtin_amdgcn_s_setprio(0);

        // hoist V^T A-frags (shared across j)
        s16x8 av[4];
#pragma unroll
        for (int t4v = 0; t4v < 4; t4v++) {
            const int row = t4v * 16 + lc;
            av[t4v] = *(const s16x8*)(vs[cur] + row * 64 + (((ksub * 4 + quad) ^ cs) << 3));
        }

        // per j: exp2 -> in-register bf16 pack -> quad-transpose -> PV (+psum MFMA)
#pragma unroll
        for (int j = 0; j < 2; j++) {
            float p0 = __builtin_amdgcn_exp2f(accST[j][0][0]);
            float p1 = __builtin_amdgcn_exp2f(accST[j][0][1]);
            float p2 = __builtin_amdgcn_exp2f(accST[j][0][2]);
            float p3 = __builtin_amdgcn_exp2f(accST[j][0][3]);
            float p4 = __builtin_amdgcn_exp2f(accST[j][1][0]);
            float p5 = __builtin_amdgcn_exp2f(accST[j][1][1]);
            float p6 = __builtin_amdgcn_exp2f(accST[j][1][2]);
            float p7 = __builtin_amdgcn_exp2f(accST[j][1][3]);

            int W00 = cvt_pk_bf16(p0, p1);   // keys q'*4+0,1   (t4k=0)
            int W01 = cvt_pk_bf16(p2, p3);   // keys q'*4+2,3   (t4k=0)
            int W10 = cvt_pk_bf16(p4, p5);   // keys 16+q'*4+0,1
            int W11 = cvt_pk_bf16(p6, p7);   // keys 16+q'*4+2,3
            // quad-transpose: after these, W00=pb0, W10=pb2, W01=pb1, W11=pb3
            asm("v_permlane32_swap_b32 %0, %1" : "+v"(W00), "+v"(W10));
            asm("v_permlane16_swap_b32 %0, %1" : "+v"(W00), "+v"(W10));
            asm("v_permlane32_swap_b32 %0, %1" : "+v"(W01), "+v"(W11));
            asm("v_permlane16_swap_b32 %0, %1" : "+v"(W01), "+v"(W11));

            union { int i[4]; s16x8 v; } pbu;
            pbu.i[0] = W00; pbu.i[1] = W01; pbu.i[2] = W10; pbu.i[3] = W11;

            __builtin_amdgcn_s_setprio(1);
#pragma unroll
            for (int t4v = 0; t4v < 4; t4v++)
                accO[j][t4v] = __builtin_amdgcn_mfma_f32_16x16x32_bf16(
                    av[t4v], pbu.v, accO[j][t4v], 0, 0, 0);
            // psum on the MFMA pipe: every output row = sum over 32 keys
            accPS[j] = __builtin_amdgcn_mfma_f32_16x16x32_bf16(
                ones.v, pbu.v, accPS[j], 0, 0, 0);
            __builtin_amdgcn_s_setprio(0);
        }

        __builtin_amdgcn_s_barrier();   // all reads of buf done before next stage
    }

    // psum per lane (replicated across quads by the ones-MFMA)
    float psum[2] = { accPS[0][0], accPS[1][0] };

    // ---- cross-wave (ksub) reduction via LDS scratch (aliases dead ks) ----
    float* sc = (float*)&ks[0][0];     // 4KB used; ks dead after loop
#pragma unroll
    for (int c = 0; c < 4; c++) {
        const int j = c >> 1, tv = (c & 1) * 2;
        __syncthreads();
        if (ksub == 1) {
            *(fv4*)(sc + ((qsub * 64 + lane) * 8))     = accO[j][tv];
            *(fv4*)(sc + ((qsub * 64 + lane) * 8 + 4)) = accO[j][tv + 1];
        }
        __syncthreads();
        if (ksub == 0) {
            accO[j][tv]     += *(fv4*)(sc + ((qsub * 64 + lane) * 8));
            accO[j][tv + 1] += *(fv4*)(sc + ((qsub * 64 + lane) * 8 + 4));
        }
    }
    __syncthreads();
    if (ksub == 1) {
        sc[(qsub * 64 + lane) * 2]     = psum[0];
        sc[(qsub * 64 + lane) * 2 + 1] = psum[1];
    }
    __syncthreads();
    if (ksub == 0) {
        psum[0] += sc[(qsub * 64 + lane) * 2];
        psum[1] += sc[(qsub * 64 + lane) * 2 + 1];

        // epilogue: normalize, write (B, T, H*64) bf16. Lane owns one q-row.
        const int b_ = bh >> 4, h_ = bh & 15;
#pragma unroll
        for (int j = 0; j < 2; j++) {
            float inv = 1.0f / psum[j];
            int row = qt * 64 + qsub * 32 + j * 16 + lc;
            ushort_t* op = o + ((size_t)b_ * T + row) * C + h_ * 64;
#pragma unroll
            for (int t4v = 0; t4v < 4; t4v++) {
                union { s16x4 v; int i[2]; } u;
                u.i[0] = cvt_pk_bf16(accO[j][t4v][0] * inv, accO[j][t4v][1] * inv);
                u.i[1] = cvt_pk_bf16(accO[j][t4v][2] * inv, accO[j][t4v][3] * inv);
                *(s16x4*)(op + t4v * 16 + quad * 4) = u.v;
            }
        }
    }
}

// ---------------------------------------------------------------------------
extern "C" void kernel_launch(void* const* d_in, const int* in_sizes, int n_in,
                              void* d_out, int out_size, void* d_ws, size_t ws_size,
                              hipStream_t stream)
{
    const float* Q  = (const float*)d_in[0];
    const float* K  = (const float*)d_in[1];
    const float* V  = (const float*)d_in[2];
    const float* Wq = (const float*)d_in[3];
    const float* bq = (const float*)d_in[4];
    const float* Wk = (const float*)d_in[5];
    const float* bk = (const float*)d_in[6];
    const float* Wv = (const float*)d_in[7];
    const float* bv = (const float*)d_in[8];
    const float* Wo = (const float*)d_in[9];
    const float* bo = (const float*)d_in[10];
    float* out = (float*)d_out;

    // ws: qkvbf 24MB (aliased as ow after gemm_qkv) | Wt 8 | qw 8 | kw 8 | vt 8
    ushort_t* qkvbf = (ushort_t*)d_ws;
    ushort_t* Wt = qkvbf + (size_t)3 * M * C;
    ushort_t* qw = Wt + (size_t)4096 * 1024;
    ushort_t* kw = qw + (size_t)M * C;
    ushort_t* vt = kw + (size_t)M * C;
    ushort_t* ow = qkvbf;                      // alias: qkv bf16 dead after gemm_qkv
    ushort_t* Wot = Wt + (size_t)3072 * 1024;

    dim3 blk(256);
    prep<<<dim3(7168), blk, 0, stream>>>(Q, K, V, Wq, Wk, Wv, Wo, qkvbf, Wt);
    gemm_qkv<<<dim3(24, 32), blk, 0, stream>>>(qkvbf, Wt, bq, bk, bv, qw, kw, vt);
    attn<<<dim3(T / 64, B * H), blk, 0, stream>>>(qw, kw, vt, ow);
    gemm_final<<<dim3(16, 64), blk, 0, stream>>>(ow, Wot, bo, out);
}